// Round 2
// baseline (629.325 us; speedup 1.0000x reference)
//
#include <hip/hip_runtime.h>

// Problem constants (match reference setup_inputs)
#define BB 128
#define HH 512
#define WW 512
#define CC 3
#define NUM_FAULTS 64

// Native clang vector type: __builtin_nontemporal_* requires a vector of
// scalar types, not HIP's struct-based int4.
typedef int ivec4 __attribute__((ext_vector_type(4)));

// ---------------------------------------------------------------------------
// Kernel 1: bulk copy images -> out. Pure streaming, 16B vector ld/st with
// nontemporal hint (data is ~800MB, far past L3; no reuse).
// ---------------------------------------------------------------------------
__global__ __launch_bounds__(256) void copy_kernel(const ivec4* __restrict__ in,
                                                   ivec4* __restrict__ out,
                                                   long n4) {
    long i = (long)blockIdx.x * blockDim.x + threadIdx.x;
    long stride = (long)gridDim.x * blockDim.x;
    for (; i < n4; i += stride) {
        ivec4 v = __builtin_nontemporal_load(&in[i]);
        __builtin_nontemporal_store(v, &out[i]);
    }
}

// ---------------------------------------------------------------------------
// Kernel 2: apply the 64 bit faults to every image, in-place on out.
// grid = B blocks, block = NUM_FAULTS threads. atomicXor handles colliding
// faults (XOR commutative/associative => identical to sequential scan).
// ---------------------------------------------------------------------------
__global__ __launch_bounds__(NUM_FAULTS) void fault_kernel(const int* __restrict__ faults,
                                                           int* __restrict__ out) {
    int f = threadIdx.x;   // fault index 0..63
    int b = blockIdx.x;    // batch index 0..127
    int fh = faults[4 * f + 0];
    int fw = faults[4 * f + 1];
    int fc = faults[4 * f + 2];
    int fb = faults[4 * f + 3];
    long idx = (long)b * ((long)HH * WW * CC)
             + (long)fh * (WW * CC)
             + (long)fw * CC
             + fc;
    atomicXor(&out[idx], 1 << fb);
}

extern "C" void kernel_launch(void* const* d_in, const int* in_sizes, int n_in,
                              void* d_out, int out_size, void* d_ws, size_t ws_size,
                              hipStream_t stream) {
    const int* images = (const int*)d_in[0];      // [B,H,W,C] int32
    const int* faults = (const int*)d_in[1];      // [NUM_FAULTS,4] int32
    int* out = (int*)d_out;                       // [B,H,W,C] int32

    long n = (long)BB * HH * WW * CC;             // 100,663,296
    long n4 = n / 4;                              // 25,165,824 ivec4

    // 2048 blocks * 256 threads = 524288 threads; each loops ~48 int4 iters.
    // Enough waves to saturate HBM on 256 CUs.
    int blocks = 2048;
    copy_kernel<<<blocks, 256, 0, stream>>>((const ivec4*)images, (ivec4*)out, n4);

    fault_kernel<<<BB, NUM_FAULTS, 0, stream>>>(faults, out);
}